// Round 1
// baseline (216.579 us; speedup 1.0000x reference)
//
#include <hip/hip_runtime.h>
#include <hip/hip_bf16.h>

typedef __attribute__((ext_vector_type(8))) short short8;
typedef __attribute__((ext_vector_type(4))) float f32x4;

#define N_BATCH 8
#define N_ROWS 32768
#define DDIM 128
#define KSLOT 64
#define EH 128
#define SCALE 0.08838834764831845f

__device__ inline unsigned short f2bf(float f){
  unsigned int u = __builtin_bit_cast(unsigned int, f);
  u = (u + 0x7FFFu + ((u >> 16) & 1u)) >> 16;
  return (unsigned short)u;
}

// ---- prep: Wk/Wv -> bf16 transposed [e][d] ----
__global__ void prep_w_kernel(const float* __restrict__ Wk, const float* __restrict__ Wv,
                              unsigned short* __restrict__ WkT, unsigned short* __restrict__ WvT){
  int e = blockIdx.x & 127;
  const float* W = (blockIdx.x & 128) ? Wv : Wk;
  unsigned short* T = (blockIdx.x & 128) ? WvT : WkT;
  int d = threadIdx.x;
  T[e * 128 + d] = f2bf(W[d * 128 + e]);
}

// ---- prep: q = S @ Wq (fp32 math) -> bf16 [b][slot][e] ----
__global__ void prep_q_kernel(const float* __restrict__ S, const float* __restrict__ Wq,
                              unsigned short* __restrict__ qbf){
  int bs = blockIdx.x; // 0..511 = b*64+slot
  __shared__ float srow[128];
  int e = threadIdx.x;
  srow[e] = S[bs * 128 + e];
  __syncthreads();
  float acc = 0.f;
  #pragma unroll 8
  for(int h = 0; h < 128; ++h) acc += srow[h] * Wq[h * 128 + e];
  qbf[bs * 128 + e] = f2bf(acc);
}

// ---- main fused kernel ----
__global__ __launch_bounds__(256, 2) void sse_main_kernel(
    const float* __restrict__ X, const unsigned short* __restrict__ WkT,
    const unsigned short* __restrict__ WvT, const unsigned short* __restrict__ qbf,
    float* __restrict__ partials, int B_n)
{
  __shared__ unsigned short Ks[64][136];   // k tile, row-major [n][e], e-contig
  __shared__ unsigned short Vts[128][72];  // v tile transposed [e][n], n-contig
  __shared__ unsigned short WTs[64][72];   // W transposed [slot][n], n-contig

  const int tid  = threadIdx.x;
  const int wave = tid >> 6;
  const int lane = tid & 63;
  const int l15  = lane & 15;
  const int g    = lane >> 4;

  const int b  = blockIdx.x / B_n;
  const int bb = blockIdx.x % B_n;

  const float* Xb = X + (size_t)b * N_ROWS * DDIM;
  const unsigned short* qb = qbf + b * KSLOT * EH;

  f32x4 sacc[8];
  #pragma unroll
  for(int i = 0; i < 8; ++i) sacc[i] = {0.f, 0.f, 0.f, 0.f};

  for(int t = bb; t < N_ROWS / 64; t += B_n){
    const int row0 = t * 64 + wave * 16;

    // ---- phase 1: k,v strips (16 rows per wave) ----
    f32x4 kacc[8], vacc[8];
    #pragma unroll
    for(int i = 0; i < 8; ++i){ kacc[i] = {0.f,0.f,0.f,0.f}; vacc[i] = {0.f,0.f,0.f,0.f}; }

    #pragma unroll
    for(int step = 0; step < 4; ++step){
      const float* px = Xb + (size_t)(row0 + l15) * DDIM + step * 32 + g * 8;
      f32x4 x0 = *reinterpret_cast<const f32x4*>(px);
      f32x4 x1 = *reinterpret_cast<const f32x4*>(px + 4);
      short8 a;
      a[0]=(short)f2bf(x0[0]); a[1]=(short)f2bf(x0[1]); a[2]=(short)f2bf(x0[2]); a[3]=(short)f2bf(x0[3]);
      a[4]=(short)f2bf(x1[0]); a[5]=(short)f2bf(x1[1]); a[6]=(short)f2bf(x1[2]); a[7]=(short)f2bf(x1[3]);
      const int boff = step * 32 + g * 8;
      #pragma unroll
      for(int et = 0; et < 8; ++et){
        short8 bk = *reinterpret_cast<const short8*>(WkT + (et * 16 + l15) * DDIM + boff);
        kacc[et] = __builtin_amdgcn_mfma_f32_16x16x32_bf16(a, bk, kacc[et], 0, 0, 0);
        short8 bv = *reinterpret_cast<const short8*>(WvT + (et * 16 + l15) * DDIM + boff);
        vacc[et] = __builtin_amdgcn_mfma_f32_16x16x32_bf16(a, bv, vacc[et], 0, 0, 0);
      }
    }

    // k -> LDS [n][e] (scalar b16), v -> LDS transposed [e][n] (packed b64)
    #pragma unroll
    for(int et = 0; et < 8; ++et){
      #pragma unroll
      for(int r = 0; r < 4; ++r)
        Ks[wave * 16 + g * 4 + r][et * 16 + l15] = f2bf(kacc[et][r]);
      ushort4 vp;
      vp.x = f2bf(vacc[et][0]); vp.y = f2bf(vacc[et][1]);
      vp.z = f2bf(vacc[et][2]); vp.w = f2bf(vacc[et][3]);
      *reinterpret_cast<ushort4*>(&Vts[et * 16 + l15][wave * 16 + g * 4]) = vp;
    }
    // no barrier needed here: Ks is intra-wave; Vts/WTs consumers are after the next barrier

    // ---- phase 2: M = k q^T (own strip), sigmoid-normalize -> WTs ----
    f32x4 macc[4];
    #pragma unroll
    for(int i = 0; i < 4; ++i) macc[i] = {0.f,0.f,0.f,0.f};
    #pragma unroll
    for(int step = 0; step < 4; ++step){
      short8 a = *reinterpret_cast<const short8*>(&Ks[wave * 16 + l15][step * 32 + g * 8]);
      #pragma unroll
      for(int st = 0; st < 4; ++st){
        short8 bq = *reinterpret_cast<const short8*>(qb + (st * 16 + l15) * EH + step * 32 + g * 8);
        macc[st] = __builtin_amdgcn_mfma_f32_16x16x32_bf16(a, bq, macc[st], 0, 0, 0);
      }
    }
    float att[4][4];
    float rowsum[4];
    #pragma unroll
    for(int st = 0; st < 4; ++st){
      #pragma unroll
      for(int r = 0; r < 4; ++r)
        att[st][r] = 1.f / (1.f + __expf(-SCALE * macc[st][r])) + 1e-8f;
    }
    #pragma unroll
    for(int r = 0; r < 4; ++r){
      float s = att[0][r] + att[1][r] + att[2][r] + att[3][r];
      s += __shfl_xor(s, 1); s += __shfl_xor(s, 2);
      s += __shfl_xor(s, 4); s += __shfl_xor(s, 8);
      rowsum[r] = s;
    }
    #pragma unroll
    for(int st = 0; st < 4; ++st){
      ushort4 wp;
      wp.x = f2bf(att[st][0] / rowsum[0]);
      wp.y = f2bf(att[st][1] / rowsum[1]);
      wp.z = f2bf(att[st][2] / rowsum[2]);
      wp.w = f2bf(att[st][3] / rowsum[3]);
      *reinterpret_cast<ushort4*>(&WTs[st * 16 + l15][wave * 16 + g * 4]) = wp;
    }
    __syncthreads();  // all waves' Vts (phase1) + WTs (phase2) complete

    // ---- phase 3: S_hat += W^T v  (wave owns slot-tile) ----
    #pragma unroll
    for(int ns = 0; ns < 2; ++ns){
      short8 a = *reinterpret_cast<const short8*>(&WTs[wave * 16 + l15][ns * 32 + g * 8]);
      #pragma unroll
      for(int et = 0; et < 8; ++et){
        short8 bvt = *reinterpret_cast<const short8*>(&Vts[et * 16 + l15][ns * 32 + g * 8]);
        sacc[et] = __builtin_amdgcn_mfma_f32_16x16x32_bf16(a, bvt, sacc[et], 0, 0, 0);
      }
    }
    __syncthreads();  // protect Vts/WTs before next iteration overwrites
  }

  // write per-block partial S_hat [64][128]
  float* po = partials + (size_t)blockIdx.x * (KSLOT * EH);
  #pragma unroll
  for(int et = 0; et < 8; ++et){
    #pragma unroll
    for(int r = 0; r < 4; ++r)
      po[(wave * 16 + g * 4 + r) * EH + et * 16 + l15] = sacc[et][r];
  }
}

// ---- deterministic reduction of partials ----
__global__ void reduce_kernel(const float* __restrict__ partials, float* __restrict__ out, int B_n){
  int idx = blockIdx.x * 256 + threadIdx.x; // 0..65535
  int b   = idx >> 13;
  int rem = idx & 8191;
  float s = 0.f;
  for(int i = 0; i < B_n; ++i) s += partials[(size_t)(b * B_n + i) * 8192 + rem];
  out[idx] = s;
}

extern "C" void kernel_launch(void* const* d_in, const int* in_sizes, int n_in,
                              void* d_out, int out_size, void* d_ws, size_t ws_size,
                              hipStream_t stream){
  const float* X  = (const float*)d_in[0];
  const float* S  = (const float*)d_in[1];
  const float* Wk = (const float*)d_in[2];
  const float* Wq = (const float*)d_in[3];
  const float* Wv = (const float*)d_in[4];
  float* out = (float*)d_out;

  char* ws = (char*)d_ws;
  unsigned short* WkT = (unsigned short*)(ws);
  unsigned short* WvT = (unsigned short*)(ws + 32768);
  unsigned short* qbf = (unsigned short*)(ws + 65536);
  float* partials     = (float*)(ws + 196608);

  int B_n = 64;  // blocks per batch; shrink if workspace is small
  while(B_n > 1 && (size_t)196608 + (size_t)N_BATCH * B_n * 8192 * 4 > ws_size) B_n >>= 1;

  hipLaunchKernelGGL(prep_w_kernel, dim3(256), dim3(128), 0, stream, Wk, Wv, WkT, WvT);
  hipLaunchKernelGGL(prep_q_kernel, dim3(512), dim3(128), 0, stream, S, Wq, qbf);
  hipLaunchKernelGGL(sse_main_kernel, dim3(N_BATCH * B_n), dim3(256), 0, stream,
                     X, WkT, WvT, qbf, partials, B_n);
  hipLaunchKernelGGL(reduce_kernel, dim3(256), dim3(256), 0, stream, partials, out, B_n);
}